// Round 2
// baseline (151.255 us; speedup 1.0000x reference)
//
#include <hip/hip_runtime.h>

#define WIRES   12
#define NSTATE  4096          // 2^12
#define QDEPTH  8
#define BLOCK   512           // EIGHT waves per block = one batch element
#define PER_T   8             // 3 local index bits; state in 16 VGPRs

using f2 = __attribute__((ext_vector_type(2))) float;

// Padded layout: amp a lives at f2-slot a + (a>>4) (rows of 16 f2,
// pitch 17). Affine in local index k for every transpose pattern ->
// ds addresses are base + compile-time immediate. Bank-pair coverage
// verified uniform (4 lanes/pair) for W1/R1/R2/R3 patterns.
__device__ __forceinline__ int slotf(int a) { return a + (a >> 4); }

// Column j of the GF(2)-linear CNOT-ring permutation of layer l:
// F = g_0∘g_1∘...∘g_11 (g_11 applied first / innermost).
constexpr int colF(int l, int j) {
    int rr = (l % (WIRES - 1)) + 1;
    int v = 1 << j;
    for (int k = WIRES - 1; k >= 0; --k) {
        int bc = 11 - k;                   // control bit
        int bt = 11 - ((k + rr) % WIRES);  // target bit
        v ^= ((v >> bc) & 1) << bt;
    }
    return v;
}
struct ColsT { int v[QDEPTH][WIRES]; };
constexpr ColsT mkCols() {
    ColsT c{};
    for (int l = 0; l < QDEPTH; ++l)
        for (int j = 0; j < WIRES; ++j) c.v[l][j] = colF(l, j);
    return c;
}
static __device__ const ColsT COLS = mkCols();   // rodata, uniform s_load

// ---- setup kernel: 96 rotation matrices -> d_ws (8 f2 per gate) ----
// Entries pre-expanded for packed math: urr = {re,re}, uw = {-im,+im}.
__global__ void mats_kernel(const float* __restrict__ wts, f2* __restrict__ mg)
{
    int t = blockIdx.x * blockDim.x + threadIdx.x;
    if (t >= QDEPTH * WIRES) return;
    float phi   = tanhf(wts[t * 3 + 0]);
    float theta = tanhf(wts[t * 3 + 1]);
    float omega = tanhf(wts[t * 3 + 2]);
    float c  = cosf(theta * 0.5f);
    float s  = sinf(theta * 0.5f);
    float a  = 0.5f * (phi + omega);
    float bm = 0.5f * (phi - omega);
    float ca = cosf(a),  sa = sinf(a);
    float cb = cosf(bm), sb = sinf(bm);
    // U00 = (c*ca, -c*sa)  U01 = (-s*cb, -s*sb)
    // U10 = (s*cb, -s*sb)  U11 = (c*ca,  c*sa)
    f2* m = mg + t * 8;
    m[0] = f2{ c * ca,  c * ca};   // u00 re,re
    m[1] = f2{ c * sa, -c * sa};   // {-im,+im}, im=-c*sa
    m[2] = f2{-s * cb, -s * cb};   // u01 re,re
    m[3] = f2{ s * sb, -s * sb};   // {-im,+im}, im=-s*sb
    m[4] = f2{ s * cb,  s * cb};   // u10 re,re
    m[5] = f2{ s * sb, -s * sb};   // {-im,+im}, im=-s*sb
    m[6] = f2{ c * ca,  c * ca};   // u11 re,re
    m[7] = f2{-c * sa,  c * sa};   // {-im,+im}, im=+c*sa
}

// 2x2 complex gate on local register bit P (P in 0..2 for PER_T=8).
// ONE asm block per TWO pairs: four accumulator chains issued
// round-robin so dependent pk-ops are 4 instructions apart.
// Perp {-y,x} folded via op_sel.
template<int P>
__device__ __forceinline__ void gate(f2 r[PER_T], const f2* __restrict__ m)
{
    const f2 u00r = m[0], u00w = m[1], u01r = m[2], u01w = m[3];
    const f2 u10r = m[4], u10w = m[5], u11r = m[6], u11w = m[7];
    #pragma unroll
    for (int pr = 0; pr < PER_T / 2; pr += 2) {
        const int k0 = ((pr >> P) << (P + 1)) | (pr & ((1 << P) - 1));
        const int k1 = k0 | (1 << P);
        const int q  = pr + 1;
        const int j0 = ((q >> P) << (P + 1)) | (q & ((1 << P) - 1));
        const int j1 = j0 | (1 << P);
        f2 a0, b0, a1, b1;
        asm("v_pk_mul_f32 %0, %4, %8\n\t"
            "v_pk_mul_f32 %1, %4, %12\n\t"
            "v_pk_mul_f32 %2, %6, %8\n\t"
            "v_pk_mul_f32 %3, %6, %12\n\t"
            "v_pk_fma_f32 %0, %4, %9, %0 op_sel:[1,0,0] op_sel_hi:[0,1,1]\n\t"
            "v_pk_fma_f32 %1, %4, %13, %1 op_sel:[1,0,0] op_sel_hi:[0,1,1]\n\t"
            "v_pk_fma_f32 %2, %6, %9, %2 op_sel:[1,0,0] op_sel_hi:[0,1,1]\n\t"
            "v_pk_fma_f32 %3, %6, %13, %3 op_sel:[1,0,0] op_sel_hi:[0,1,1]\n\t"
            "v_pk_fma_f32 %0, %5, %10, %0\n\t"
            "v_pk_fma_f32 %1, %5, %14, %1\n\t"
            "v_pk_fma_f32 %2, %7, %10, %2\n\t"
            "v_pk_fma_f32 %3, %7, %14, %3\n\t"
            "v_pk_fma_f32 %0, %5, %11, %0 op_sel:[1,0,0] op_sel_hi:[0,1,1]\n\t"
            "v_pk_fma_f32 %1, %5, %15, %1 op_sel:[1,0,0] op_sel_hi:[0,1,1]\n\t"
            "v_pk_fma_f32 %2, %7, %11, %2 op_sel:[1,0,0] op_sel_hi:[0,1,1]\n\t"
            "v_pk_fma_f32 %3, %7, %15, %3 op_sel:[1,0,0] op_sel_hi:[0,1,1]"
            : "=&v"(a0), "=&v"(b0), "=&v"(a1), "=&v"(b1)
            : "v"(r[k0]), "v"(r[k1]), "v"(r[j0]), "v"(r[j1]),
              "v"(u00r), "v"(u00w), "v"(u01r), "v"(u01w),
              "v"(u10r), "v"(u10w), "v"(u11r), "v"(u11w));
        r[k0] = a0; r[k1] = b0; r[j0] = a1; r[j1] = b1;
    }
}

// EIGHT waves = one batch element. g = threadIdx.x (9 bits).
// Canonical: r[k] = amp[(g<<3)|k]  (amp bit b <-> wire 11-b).
// Per layer, 4 phases of 3 wires each:
//   P1: wires 9..11  (amp bits 2..0 local)
//   T1: k <- amp bits 5..3   P2: wires 6..8
//   T2: k <- amp bits 8..6   P3: wires 3..5
//   T3: k <- amp bits 11..9  P4: wires 0..2
//   T4: scatter canonical + gather canonical ∘ F (CNOT ring folded in)
// Every W stores amp a at slotf(a); every R reads slotf(needed amp).
// No barrier between an R round and the W round that rewrites the same
// per-lane slot set (bijective per-lane map identical for both).
__global__ __launch_bounds__(BLOCK, 8) void qsim_kernel(
    const float* __restrict__ x,
    const f2*    __restrict__ mats_g,
    const int*   __restrict__ reps_ptr,
    float*       __restrict__ out,
    int write_mode)
{
    __shared__ f2 st[4352];                          // 34816 B -> 4 blocks/CU

    const int g   = threadIdx.x;                     // 0..511
    const int b   = blockIdx.x;
    const int m3  = (g >> 3) & 7;
    // W1 base:  slotf((g<<3)|k)            = 8g+(g>>1) + k
    // R1 base:  slotf((g6<<6)|(k<<3)|g3)   = 68*g6+g3  + 8k+(k>>1)
    // R2 base:  slotf((k<<6..)|..)         = 544*t3+8*m3+(m3>>1)+b3 + 68k
    // R3 base:  slotf((k<<9)|g)            = g+(g>>4)  + 544k
    const int w1b = 8 * g + (g >> 1);
    const int r1b = 68 * (g >> 3) + (g & 7);
    const int r2b = 544 * (g >> 6) + 8 * m3 + (m3 >> 1) + (g & 7);
    const int r3b = g + (g >> 4);

    // ---- load: lane g holds amps (g<<3)|k, k=0..7 (32B contiguous) ----
    const float4* xb4 = (const float4*)(x + (size_t)b * NSTATE) + g * 2;
    f2 r[PER_T];
    #pragma unroll
    for (int c = 0; c < 2; ++c) {
        float4 v = xb4[c];
        r[4*c+0] = f2{v.x, 0.f};
        r[4*c+1] = f2{v.y, 0.f};
        r[4*c+2] = f2{v.z, 0.f};
        r[4*c+3] = f2{v.w, 0.f};
    }

    const int reps = reps_ptr[0];
    for (int rep = 0; rep < reps; ++rep) {
        #pragma unroll 1
        for (int l = 0; l < QDEPTH; ++l) {
            const f2* M = mats_g + l * WIRES * 8;   // wave-uniform -> s_load

            // Phase 1: wires 9..11 on local bits 2..0 (bit = 11-wire)
            gate<2>(r, M + 9*8); gate<1>(r, M + 10*8); gate<0>(r, M + 11*8);

            #pragma unroll
            for (int k = 0; k < PER_T; ++k) st[w1b + k] = r[k];
            __syncthreads();
            #pragma unroll
            for (int k = 0; k < PER_T; ++k) r[k] = st[r1b + 8*k + (k >> 1)];
            // no barrier: W2 rewrites exactly the slots this lane just read

            // Phase 2: wires 6..8 (amp bits 5..3 local)
            gate<2>(r, M + 6*8); gate<1>(r, M + 7*8); gate<0>(r, M + 8*8);

            #pragma unroll
            for (int k = 0; k < PER_T; ++k) st[r1b + 8*k + (k >> 1)] = r[k];
            __syncthreads();
            #pragma unroll
            for (int k = 0; k < PER_T; ++k) r[k] = st[r2b + 68*k];

            // Phase 3: wires 3..5 (amp bits 8..6 local)
            gate<2>(r, M + 3*8); gate<1>(r, M + 4*8); gate<0>(r, M + 5*8);

            #pragma unroll
            for (int k = 0; k < PER_T; ++k) st[r2b + 68*k] = r[k];
            __syncthreads();
            #pragma unroll
            for (int k = 0; k < PER_T; ++k) r[k] = st[r3b + 544*k];

            // Phase 4: wires 0..2 (amp bits 11..9 local)
            gate<2>(r, M + 0*8); gate<1>(r, M + 1*8); gate<0>(r, M + 2*8);

            #pragma unroll
            for (int k = 0; k < PER_T; ++k) st[r3b + 544*k] = r[k];
            __syncthreads();

            // T4 gather: r[k] = old_amp[F((g<<3)|k)] -> canonical again
            int Fg = 0;
            #pragma unroll
            for (int j = 0; j < 9; ++j)
                Fg ^= ((g >> j) & 1) ? COLS.v[l][3 + j] : 0;
            const int c0 = COLS.v[l][0], c1 = COLS.v[l][1], c2 = COLS.v[l][2];
            #pragma unroll
            for (int k = 0; k < PER_T; ++k) {
                int ck = ((k & 1) ? c0 : 0) ^ ((k & 2) ? c1 : 0) ^
                         ((k & 4) ? c2 : 0);
                r[k] = st[slotf(Fg ^ ck)];
            }
            __syncthreads();   // protect next layer's W1 scatter
        }
    }

    // ---- write out (r is canonical: 8 consecutive amps per lane) ----
    if (write_mode == 0) {
        // harness views complex output as float32 real part
        float4* ob4 = (float4*)(out + (size_t)b * NSTATE) + g * 2;
        #pragma unroll
        for (int c = 0; c < 2; ++c)
            ob4[c] = make_float4(r[4*c].x, r[4*c+1].x, r[4*c+2].x, r[4*c+3].x);
    } else {
        float4* ob4 = (float4*)((float2*)out + (size_t)b * NSTATE) + g * 4;
        #pragma unroll
        for (int k = 0; k < PER_T; k += 2)
            ob4[k >> 1] = make_float4(r[k].x, r[k].y, r[k+1].x, r[k+1].y);
    }
}

extern "C" void kernel_launch(void* const* d_in, const int* in_sizes, int n_in,
                              void* d_out, int out_size, void* d_ws, size_t ws_size,
                              hipStream_t stream) {
    const float* x    = (const float*)d_in[0];
    const float* wts  = (const float*)d_in[1];
    const int*   reps = (const int*)d_in[2];
    float*       out  = (float*)d_out;
    f2*          mg   = (f2*)d_ws;            // 96 gates * 8 f2 = 3 KB scratch
    (void)in_sizes; (void)n_in; (void)ws_size;

    const int write_mode = (out_size >= 2 * 1024 * NSTATE) ? 1 : 0;

    mats_kernel<<<1, 128, 0, stream>>>(wts, mg);
    qsim_kernel<<<1024, BLOCK, 0, stream>>>(x, mg, reps, out, write_mode);
}

// Round 3
// 150.969 us; speedup vs baseline: 1.0019x; 1.0019x over previous
//
#include <hip/hip_runtime.h>

#define WIRES   12
#define NSTATE  4096          // 2^12
#define QDEPTH  8
#define BLOCK   256           // 4 waves; block handles TWO batch elements
#define PER_T   16            // 4 local index bits per element; 16 f2 regs each

using f2 = __attribute__((ext_vector_type(2))) float;

// Pitch-17 padded layout per element buffer: amp a -> f2-slot a + (a>>4).
// Affine in local index k for all three transpose patterns -> ds
// addresses are base + compile-time immediate. Bank-pair coverage is
// uniform (4 lanes/pair) for W1/R1/R2; only the F-gather is scrambled.
__device__ __forceinline__ int slotf(int a) { return a + (a >> 4); }

// Column j of the GF(2)-linear CNOT-ring permutation of layer l:
// F = g_0∘g_1∘...∘g_11 (g_11 applied first / innermost).
constexpr int colF(int l, int j) {
    int rr = (l % (WIRES - 1)) + 1;
    int v = 1 << j;
    for (int k = WIRES - 1; k >= 0; --k) {
        int bc = 11 - k;                   // control bit
        int bt = 11 - ((k + rr) % WIRES);  // target bit
        v ^= ((v >> bc) & 1) << bt;
    }
    return v;
}
struct ColsT { int v[QDEPTH][WIRES]; };
constexpr ColsT mkCols() {
    ColsT c{};
    for (int l = 0; l < QDEPTH; ++l)
        for (int j = 0; j < WIRES; ++j) c.v[l][j] = colF(l, j);
    return c;
}
static __device__ const ColsT COLS = mkCols();   // rodata, uniform s_load

// ---- setup kernel: 96 rotation matrices -> d_ws (8 f2 per gate) ----
// Entries pre-expanded for packed math: urr = {re,re}, uw = {-im,+im}.
__global__ void mats_kernel(const float* __restrict__ wts, f2* __restrict__ mg)
{
    int t = blockIdx.x * blockDim.x + threadIdx.x;
    if (t >= QDEPTH * WIRES) return;
    float phi   = tanhf(wts[t * 3 + 0]);
    float theta = tanhf(wts[t * 3 + 1]);
    float omega = tanhf(wts[t * 3 + 2]);
    float c  = cosf(theta * 0.5f);
    float s  = sinf(theta * 0.5f);
    float a  = 0.5f * (phi + omega);
    float bm = 0.5f * (phi - omega);
    float ca = cosf(a),  sa = sinf(a);
    float cb = cosf(bm), sb = sinf(bm);
    // U00 = (c*ca, -c*sa)  U01 = (-s*cb, -s*sb)
    // U10 = (s*cb, -s*sb)  U11 = (c*ca,  c*sa)
    f2* m = mg + t * 8;
    m[0] = f2{ c * ca,  c * ca};   // u00 re,re
    m[1] = f2{ c * sa, -c * sa};   // {-im,+im}, im=-c*sa
    m[2] = f2{-s * cb, -s * cb};   // u01 re,re
    m[3] = f2{ s * sb, -s * sb};   // {-im,+im}, im=-s*sb
    m[4] = f2{ s * cb,  s * cb};   // u10 re,re
    m[5] = f2{ s * sb, -s * sb};   // {-im,+im}, im=-s*sb
    m[6] = f2{ c * ca,  c * ca};   // u11 re,re
    m[7] = f2{-c * sa,  c * sa};   // {-im,+im}, im=+c*sa
}

// 2x2 complex gate on local register bit P. ONE asm block per TWO pairs:
// four accumulator chains (a0,b0,a1,b1) issued round-robin so dependent
// pk-ops are 4 instructions apart. Perp {-y,x} folded via op_sel.
template<int P>
__device__ __forceinline__ void gate(f2 r[PER_T], const f2* __restrict__ m)
{
    const f2 u00r = m[0], u00w = m[1], u01r = m[2], u01w = m[3];
    const f2 u10r = m[4], u10w = m[5], u11r = m[6], u11w = m[7];
    #pragma unroll
    for (int pr = 0; pr < PER_T / 2; pr += 2) {
        const int k0 = ((pr >> P) << (P + 1)) | (pr & ((1 << P) - 1));
        const int k1 = k0 | (1 << P);
        const int q  = pr + 1;
        const int j0 = ((q >> P) << (P + 1)) | (q & ((1 << P) - 1));
        const int j1 = j0 | (1 << P);
        f2 a0, b0, a1, b1;
        asm("v_pk_mul_f32 %0, %4, %8\n\t"
            "v_pk_mul_f32 %1, %4, %12\n\t"
            "v_pk_mul_f32 %2, %6, %8\n\t"
            "v_pk_mul_f32 %3, %6, %12\n\t"
            "v_pk_fma_f32 %0, %4, %9, %0 op_sel:[1,0,0] op_sel_hi:[0,1,1]\n\t"
            "v_pk_fma_f32 %1, %4, %13, %1 op_sel:[1,0,0] op_sel_hi:[0,1,1]\n\t"
            "v_pk_fma_f32 %2, %6, %9, %2 op_sel:[1,0,0] op_sel_hi:[0,1,1]\n\t"
            "v_pk_fma_f32 %3, %6, %13, %3 op_sel:[1,0,0] op_sel_hi:[0,1,1]\n\t"
            "v_pk_fma_f32 %0, %5, %10, %0\n\t"
            "v_pk_fma_f32 %1, %5, %14, %1\n\t"
            "v_pk_fma_f32 %2, %7, %10, %2\n\t"
            "v_pk_fma_f32 %3, %7, %14, %3\n\t"
            "v_pk_fma_f32 %0, %5, %11, %0 op_sel:[1,0,0] op_sel_hi:[0,1,1]\n\t"
            "v_pk_fma_f32 %1, %5, %15, %1 op_sel:[1,0,0] op_sel_hi:[0,1,1]\n\t"
            "v_pk_fma_f32 %2, %7, %11, %2 op_sel:[1,0,0] op_sel_hi:[0,1,1]\n\t"
            "v_pk_fma_f32 %3, %7, %15, %3 op_sel:[1,0,0] op_sel_hi:[0,1,1]"
            : "=&v"(a0), "=&v"(b0), "=&v"(a1), "=&v"(b1)
            : "v"(r[k0]), "v"(r[k1]), "v"(r[j0]), "v"(r[j1]),
              "v"(u00r), "v"(u00w), "v"(u01r), "v"(u01w),
              "v"(u10r), "v"(u10w), "v"(u11r), "v"(u11w));
        r[k0] = a0; r[k1] = b0; r[j0] = a1; r[j1] = b1;
    }
}

// 4 waves = TWO batch elements (A = 2b, B = 2b+1), PER_T=16 each.
// Canonical: r[k] = amp[(g<<4)|k]  (amp bit b <-> wire 11-b).
// Per layer, 3 phases of 4 wires each (round-1 geometry), but element
// B's pure-VALU gate work is interleaved with element A's LDS rounds
// (and vice versa) so the LDS pipe hides under VALU *within* a wave --
// round 1/2 showed barrier-lockstep serializes them across waves.
// No barrier between an R round and the W round that rewrites the same
// per-lane slot set (bijective per-lane map identical for both).
__global__ __launch_bounds__(BLOCK, 2) void qsim_kernel(
    const float* __restrict__ x,
    const f2*    __restrict__ mats_g,
    const int*   __restrict__ reps_ptr,
    float*       __restrict__ out,
    int write_mode)
{
    __shared__ f2 st[2 * 4352];                      // 69632 B -> 2 blocks/CU
    f2* const sA = st;
    f2* const sB = st + 4352;

    const int g   = threadIdx.x;
    const int eA  = blockIdx.x * 2;
    const int eB  = eA + 1;
    const int ghi = g >> 4, glo = g & 15;
    const int w1b = 17 * g;                // slot((g<<4)|k)          = 17g + k
    const int rb1 = 272 * ghi + glo;       // slot((ghi<<8)|(k<<4)|glo) - 17k
    const int rb2 = 17 * ghi + glo;        // slot((k<<8)|(ghi<<4)|glo) - 272k

    // ---- load: lane g holds amps (g<<4)|k for both elements ----
    const float4* xA4 = (const float4*)(x + (size_t)eA * NSTATE) + g * 4;
    const float4* xB4 = (const float4*)(x + (size_t)eB * NSTATE) + g * 4;
    f2 rA[PER_T], rB[PER_T];
    #pragma unroll
    for (int c = 0; c < 4; ++c) {
        float4 va = xA4[c];
        rA[4*c+0] = f2{va.x, 0.f}; rA[4*c+1] = f2{va.y, 0.f};
        rA[4*c+2] = f2{va.z, 0.f}; rA[4*c+3] = f2{va.w, 0.f};
        float4 vb = xB4[c];
        rB[4*c+0] = f2{vb.x, 0.f}; rB[4*c+1] = f2{vb.y, 0.f};
        rB[4*c+2] = f2{vb.z, 0.f}; rB[4*c+3] = f2{vb.w, 0.f};
    }

    const int reps = reps_ptr[0];
    for (int rep = 0; rep < reps; ++rep) {
        #pragma unroll 1
        for (int l = 0; l < QDEPTH; ++l) {
            const f2* M = mats_g + l * WIRES * 8;   // wave-uniform -> s_load

            // Phase 1: wires 8..11 on local bits 3..0 (bit = 11-wire).
            // A's W1 ds_writes drain while B's gates execute.
            gate<3>(rA, M + 8*8);  gate<2>(rA, M + 9*8);
            gate<1>(rA, M + 10*8); gate<0>(rA, M + 11*8);
            #pragma unroll
            for (int k = 0; k < PER_T; ++k) sA[w1b + k] = rA[k];
            gate<3>(rB, M + 8*8);  gate<2>(rB, M + 9*8);
            gate<1>(rB, M + 10*8); gate<0>(rB, M + 11*8);
            #pragma unroll
            for (int k = 0; k < PER_T; ++k) sB[w1b + k] = rB[k];
            __syncthreads();

            // R1 both elements issued back-to-back; A's gates wait only
            // on A's (older) reads, B's reads finish under A's gates.
            #pragma unroll
            for (int k = 0; k < PER_T; ++k) rA[k] = sA[rb1 + 17 * k];
            #pragma unroll
            for (int k = 0; k < PER_T; ++k) rB[k] = sB[rb1 + 17 * k];

            // Phase 2: wires 4..7 (amp bits 7..4 local)
            gate<3>(rA, M + 4*8); gate<2>(rA, M + 5*8);
            gate<1>(rA, M + 6*8); gate<0>(rA, M + 7*8);
            #pragma unroll
            for (int k = 0; k < PER_T; ++k) sA[rb1 + 17 * k] = rA[k];
            gate<3>(rB, M + 4*8); gate<2>(rB, M + 5*8);
            gate<1>(rB, M + 6*8); gate<0>(rB, M + 7*8);
            #pragma unroll
            for (int k = 0; k < PER_T; ++k) sB[rb1 + 17 * k] = rB[k];
            __syncthreads();

            #pragma unroll
            for (int k = 0; k < PER_T; ++k) rA[k] = sA[rb2 + 272 * k];
            #pragma unroll
            for (int k = 0; k < PER_T; ++k) rB[k] = sB[rb2 + 272 * k];

            // Phase 3: wires 0..3 (amp bits 11..8 local)
            gate<3>(rA, M + 0*8); gate<2>(rA, M + 1*8);
            gate<1>(rA, M + 2*8); gate<0>(rA, M + 3*8);
            #pragma unroll
            for (int k = 0; k < PER_T; ++k) sA[rb2 + 272 * k] = rA[k];
            gate<3>(rB, M + 0*8); gate<2>(rB, M + 1*8);
            gate<1>(rB, M + 2*8); gate<0>(rB, M + 3*8);
            #pragma unroll
            for (int k = 0; k < PER_T; ++k) sB[rb2 + 272 * k] = rB[k];
            __syncthreads();

            // F-gather: r[k] = old_amp[F((g<<4)|k)] -> canonical again
            int Fg = 0;
            #pragma unroll
            for (int j = 0; j < 8; ++j)
                Fg ^= ((g >> j) & 1) ? COLS.v[l][4 + j] : 0;
            const int c0 = COLS.v[l][0], c1 = COLS.v[l][1];
            const int c2 = COLS.v[l][2], c3 = COLS.v[l][3];
            #pragma unroll
            for (int k = 0; k < PER_T; ++k) {
                int ck = ((k & 1) ? c0 : 0) ^ ((k & 2) ? c1 : 0) ^
                         ((k & 4) ? c2 : 0) ^ ((k & 8) ? c3 : 0);
                int s  = slotf(Fg ^ ck);
                rA[k] = sA[s];
                rB[k] = sB[s];
            }
            __syncthreads();   // protect next layer's W1 scatter
        }
    }

    // ---- write out (r is canonical: 16 consecutive amps per lane) ----
    if (write_mode == 0) {
        // harness views complex output as float32 real part
        float4* oA4 = (float4*)(out + (size_t)eA * NSTATE) + g * 4;
        float4* oB4 = (float4*)(out + (size_t)eB * NSTATE) + g * 4;
        #pragma unroll
        for (int c = 0; c < 4; ++c) {
            oA4[c] = make_float4(rA[4*c].x, rA[4*c+1].x, rA[4*c+2].x, rA[4*c+3].x);
            oB4[c] = make_float4(rB[4*c].x, rB[4*c+1].x, rB[4*c+2].x, rB[4*c+3].x);
        }
    } else {
        float4* oA4 = (float4*)((float2*)out + (size_t)eA * NSTATE) + g * 8;
        float4* oB4 = (float4*)((float2*)out + (size_t)eB * NSTATE) + g * 8;
        #pragma unroll
        for (int k = 0; k < PER_T; k += 2) {
            oA4[k >> 1] = make_float4(rA[k].x, rA[k].y, rA[k+1].x, rA[k+1].y);
            oB4[k >> 1] = make_float4(rB[k].x, rB[k].y, rB[k+1].x, rB[k+1].y);
        }
    }
}

extern "C" void kernel_launch(void* const* d_in, const int* in_sizes, int n_in,
                              void* d_out, int out_size, void* d_ws, size_t ws_size,
                              hipStream_t stream) {
    const float* x    = (const float*)d_in[0];
    const float* wts  = (const float*)d_in[1];
    const int*   reps = (const int*)d_in[2];
    float*       out  = (float*)d_out;
    f2*          mg   = (f2*)d_ws;            // 96 gates * 8 f2 = 3 KB scratch
    (void)in_sizes; (void)n_in; (void)ws_size;

    const int write_mode = (out_size >= 2 * 1024 * NSTATE) ? 1 : 0;

    mats_kernel<<<1, 128, 0, stream>>>(wts, mg);
    qsim_kernel<<<512, BLOCK, 0, stream>>>(x, mg, reps, out, write_mode);
}